// Round 1
// 329.453 us; speedup vs baseline: 1.1068x; 1.1068x over previous
//
#include <hip/hip_runtime.h>
#include <hip/hip_bf16.h>
#include <math.h>

// N=64, C_IN=C_OUT=64, T=300, V=25, INTER_C=16, NUM_SUBSET=3
// Block = (n, 5 t-values) -> 125 (t,v) cols, padded to 128 (8 16-tiles / 4 32-tiles).
// Phases per subset: [PQ-GEMM 16x16] bar [S-GEMM + reg-softmax -> sv] bar
// [Z-GEMM 32x32x16 + fold]. 28.8 KB LDS -> 5 blocks/CU.
//
// v5 changes vs v4 (theory: issue/latency-bound, VALU dominated by f32->bf16 cvt):
//  1. prep kernel pre-converts a_w/b_w/g_w to bf16 in d_ws (removes per-block,
//     per-iteration manual RNE conversion -- ~900 VALU/thread), precomputes
//     colA and fused BN scale/shift (incl. summed g_b).
//  2. remaining conversions use hw v_cvt_pk_bf16_f32 via scalar bf16 cast.
//  3. XCD-bijective block remap: all 60 t-chunks of one n stay on one XCD's L2
//     so the 500B-span write boundaries (shared 64B lines between t-neighbors)
//     are RMW'd in one L2 instead of two non-coherent ones.

typedef __attribute__((ext_vector_type(8)))  short bf8;
typedef __attribute__((ext_vector_type(4)))  short bf4;
typedef __attribute__((ext_vector_type(4)))  float f4;
typedef __attribute__((ext_vector_type(16))) float f16v;

#define TT    5
#define COLS  125
#define COLSP 128
#define XROW  72   // shorts per Xb row (mult of 8 -> 16B-aligned bf8 reads)
#define PQROW 40   // shorts per PQt row (P 0:16, Q 16:32, pad)

// workspace layout (bytes)
#define WS_AW    0        // [3][16][64] bf16 = 6144
#define WS_BW    6144     // [3][16][64] bf16 = 6144
#define WS_GW    12288    // [3][64][64] bf16 = 24576
#define WS_COLA  36864    // [75] f32 = 300 (pad to 512)
#define WS_SCL   37376    // [64] f32
#define WS_SHF   37632    // [64] f32
#define WS_END   37888

__device__ __forceinline__ short f2bf(float f) {
  // scalar cast -> compiler emits hw v_cvt_bf16 (RNE), packs pairs (m240)
  __hip_bfloat16 h = __float2bfloat16(f);
  return __builtin_bit_cast(short, h);
}
__device__ __forceinline__ float bf2f(short s) {
  union { unsigned u; float f; } v;
  v.u = ((unsigned)(unsigned short)s) << 16;
  return v.f;
}
__device__ __forceinline__ float rsum16(float v) {
  v += __shfl_xor(v, 1);
  v += __shfl_xor(v, 2);
  v += __shfl_xor(v, 4);
  v += __shfl_xor(v, 8);
  return v;
}

// ---------------- prep: weights->bf16, colA, fused BN scale/shift ----------------
__global__ void tagc_prep(
    const float* __restrict__ A,    const float* __restrict__ G,
    const float* __restrict__ g_w,  const float* __restrict__ g_b,
    const float* __restrict__ a_w,  const float* __restrict__ b_w,
    const float* __restrict__ bn_g, const float* __restrict__ bn_b,
    const float* __restrict__ bn_m, const float* __restrict__ bn_v,
    short* __restrict__ aw_bf, short* __restrict__ bw_bf,
    short* __restrict__ gw_bf, float* __restrict__ colA3,
    float* __restrict__ scl,   float* __restrict__ shf2)
{
  const int b = blockIdx.x, tid = threadIdx.x;
  if (b < 12) {                       // g_w: 12288 elems, 1024/block
    int base = b * 1024 + tid * 4;
    f4 v = *(const f4*)(g_w + base);
    bf4 o;
    #pragma unroll
    for (int r = 0; r < 4; ++r) o[r] = f2bf(v[r]);
    *(bf4*)(gw_bf + base) = o;
  } else if (b == 12) {               // a_w: 3072 elems
    #pragma unroll
    for (int g = 0; g < 3; ++g) {
      int base = g * 1024 + tid * 4;
      f4 v = *(const f4*)(a_w + base);
      bf4 o;
      #pragma unroll
      for (int r = 0; r < 4; ++r) o[r] = f2bf(v[r]);
      *(bf4*)(aw_bf + base) = o;
    }
  } else if (b == 13) {               // b_w: 3072 elems
    #pragma unroll
    for (int g = 0; g < 3; ++g) {
      int base = g * 1024 + tid * 4;
      f4 v = *(const f4*)(b_w + base);
      bf4 o;
      #pragma unroll
      for (int r = 0; r < 4; ++r) o[r] = f2bf(v[r]);
      *(bf4*)(bw_bf + base) = o;
    }
  } else if (b == 14) {               // colA[i][v] = sum_a (A+G)[i][a][v]
    if (tid < 75) {
      int i = tid / 25, v = tid - 25 * i;
      float s = 0.f;
      for (int a = 0; a < 25; ++a)
        s += A[i * 625 + a * 25 + v] + G[i * 625 + a * 25 + v];
      colA3[tid] = s;
    }
  } else {                            // fused BN: scl, shf2 = bb - bm*scl + (sum g_b)*scl
    if (tid < 64) {
      float sc  = bn_g[tid] * rsqrtf(bn_v[tid] + 1e-5f);
      float gbs = g_b[tid] + g_b[64 + tid] + g_b[128 + tid];
      scl[tid]  = sc;
      shf2[tid] = bn_b[tid] - bn_m[tid] * sc + gbs * sc;
    }
  }
}

// ---------------- main ----------------
__launch_bounds__(256, 5)
__global__ void tagc_v5_kernel(
    const float* __restrict__ x,      // [64,64,300,25]
    const float* __restrict__ a_b,    // [3,16]
    const float* __restrict__ b_b,    // [3,16]
    const short* __restrict__ aw_bf,  // [3,16,64] bf16
    const short* __restrict__ bw_bf,  // [3,16,64] bf16
    const short* __restrict__ gw_bf,  // [3,64,64] bf16
    const float* __restrict__ colA3,  // [75]
    const float* __restrict__ sclp,   // [64]
    const float* __restrict__ shf2p,  // [64]
    float* __restrict__ out)
{
  __shared__ __align__(16) short Xb[COLSP * XROW];   // [col][c] bf16, zero-padded cols
  __shared__ __align__(16) short PQt[COLSP * PQROW]; // [col][0:16 P | 16:32 Q]
  __shared__ float sv[TT * 28];
  __shared__ float colA[75];

  const int tid  = threadIdx.x;
  const int wave = tid >> 6;
  const int lane = tid & 63;
  const int l15  = lane & 15;
  const int quad = lane >> 4;
  const int l31  = lane & 31;
  const int hl   = lane >> 5;

  // XCD-bijective remap (3840 blocks % 8 == 0): lin%8 = XCD; give each XCD
  // 8 whole n-stripes so t-adjacent blocks (shared write cache lines) stay
  // on one L2.
  const int lin = blockIdx.y * 60 + blockIdx.x;
  const int idx = lin >> 3;
  const int n   = ((lin & 7) << 3) + idx / 60;
  const int t0  = (idx % 60) * TT;

  if (tid < 75) colA[tid] = colA3[tid];

  // stage X -> Xb (bf16, [col][c])
  {
    const float* xb = x + (long)n * 480000 + t0 * 25;
    #pragma unroll
    for (int k = 0; k < 8; ++k) {
      int idxs = k * 256 + tid;         // < 2048 = 16 * 128
      int c4  = idxs >> 7;              // 0..15
      int col = idxs & 127;
      bool ok = (col < COLS);
      bf4 wv;
      #pragma unroll
      for (int j = 0; j < 4; ++j) {
        float g = ok ? xb[(4 * c4 + j) * 7500 + col] : 0.f;
        wv[j] = f2bf(g);
      }
      *(bf4*)&Xb[col * XROW + 4 * c4] = wv;
    }
  }

  f16v R0, R1;
  #pragma unroll
  for (int r = 0; r < 16; ++r) { R0[r] = 0.f; R1[r] = 0.f; }

  __syncthreads();

  for (int i = 0; i < 3; ++i) {
    // ========== Phase A: PQ-GEMM [32 x 64] * [64 x 128], 16x16x32 ==========
    {
      const int mt  = wave & 1;                // 0 -> P (a_w), 1 -> Q (b_w)
      const int ntb = (wave >> 1) * 4;
      const short* Wb = (mt ? bw_bf : aw_bf) + i * 1024;
      const float* Bv = (mt ? b_b : a_b) + i * 16;

      bf8 Af[2];
      Af[0] = *(const bf8*)(Wb + l15 * 64 + quad * 8);
      Af[1] = *(const bf8*)(Wb + l15 * 64 + 32 + quad * 8);

      float bias[4];
      #pragma unroll
      for (int r = 0; r < 4; ++r) bias[r] = Bv[quad * 4 + r];

      #pragma unroll
      for (int j = 0; j < 4; ++j) {
        int nt = ntb + j;
        bf8 B0 = *(const bf8*)&Xb[(nt * 16 + l15) * XROW + quad * 8];
        bf8 B1 = *(const bf8*)&Xb[(nt * 16 + l15) * XROW + 32 + quad * 8];
        f4 acc = {0.f, 0.f, 0.f, 0.f};
        acc = __builtin_amdgcn_mfma_f32_16x16x32_bf16(Af[0], B0, acc, 0, 0, 0);
        acc = __builtin_amdgcn_mfma_f32_16x16x32_bf16(Af[1], B1, acc, 0, 0, 0);
        int col = nt * 16 + l15;
        bf4 w;
        #pragma unroll
        for (int r = 0; r < 4; ++r) w[r] = f2bf(acc[r] + bias[r]);
        *(bf4*)&PQt[col * PQROW + mt * 16 + quad * 4] = w;
      }
    }
    __syncthreads();

    // ========== Phase B: S-GEMM + in-register softmax (no max-sub) ==========
    for (int tsel = wave; tsel < TT; tsel += 4) {
      f4 sacc[2][2];
      #pragma unroll
      for (int am = 0; am < 2; ++am) {
        bf8 Afr = {0,0,0,0,0,0,0,0};
        if (quad < 2 && (am * 16 + l15) < 25)
          Afr = *(const bf8*)&PQt[(tsel * 25 + am * 16 + l15) * PQROW + quad * 8];
        #pragma unroll
        for (int wm = 0; wm < 2; ++wm) {
          bf8 Bfr = {0,0,0,0,0,0,0,0};
          if (quad < 2 && (wm * 16 + l15) < 25)
            Bfr = *(const bf8*)&PQt[(tsel * 25 + wm * 16 + l15) * PQROW + 16 + quad * 8];
          f4 z = {0.f, 0.f, 0.f, 0.f};
          sacc[am][wm] = __builtin_amdgcn_mfma_f32_16x16x32_bf16(Afr, Bfr, z, 0, 0, 0);
        }
      }
      const bool w1ok = (l15 < 9);
      float cs0 = 0.f, cs1 = 0.f;
      #pragma unroll
      for (int am = 0; am < 2; ++am) {
        #pragma unroll
        for (int r = 0; r < 4; ++r) {
          float e0 = __expf(sacc[am][0][r] * 0.0625f);
          float e1 = w1ok ? __expf(sacc[am][1][r] * 0.0625f) : 0.f;
          float d  = rsum16(e0 + e1);
          float rd = 1.f / d;
          int a = am * 16 + quad * 4 + r;
          if (a < 25) { cs0 += e0 * rd; cs1 += e1 * rd; }
        }
      }
      cs0 += __shfl_xor(cs0, 16); cs0 += __shfl_xor(cs0, 32);
      cs1 += __shfl_xor(cs1, 16); cs1 += __shfl_xor(cs1, 32);
      if (quad == 0) {
        sv[tsel * 28 + l15] = cs0 + colA[i * 25 + l15];
        if (l15 < 9)
          sv[tsel * 28 + 16 + l15] = cs1 + colA[i * 25 + 16 + l15];
      }
    }
    __syncthreads();

    // ========== Phase C: Z-GEMM 32x32x16 + immediate fold into R ==========
    {
      const int trow = wave >> 1;   // o-tile (0: o 0..31, 1: o 32..63)
      const int tcb  = wave & 1;    // col-tiles tcb, tcb+2
      const short* gp = gw_bf + i * 4096 + (trow * 32 + l31) * 64;
      bf8 Ag[4];
      #pragma unroll
      for (int kk = 0; kk < 4; ++kk)
        Ag[kk] = *(const bf8*)(gp + kk * 16 + hl * 8);

      #pragma unroll
      for (int tix = 0; tix < 2; ++tix) {
        int colb = (tcb + tix * 2) * 32;
        f16v za;
        #pragma unroll
        for (int r = 0; r < 16; ++r) za[r] = 0.f;
        #pragma unroll
        for (int kk = 0; kk < 4; ++kk) {
          bf8 Bf = *(const bf8*)&Xb[(colb + l31) * XROW + kk * 16 + hl * 8];
          za = __builtin_amdgcn_mfma_f32_32x32x16_bf16(Ag[kk], Bf, za, 0, 0, 0);
        }
        int col  = colb + l31;
        int colc = col < COLS ? col : (COLS - 1);
        int t = colc / 25, v = colc - 25 * t;
        float sval = sv[t * 28 + v];
        if (tix == 0) {
          #pragma unroll
          for (int r = 0; r < 16; ++r) R0[r] += za[r] * sval;
        } else {
          #pragma unroll
          for (int r = 0; r < 16; ++r) R1[r] += za[r] * sval;
        }
      }
    }
    // no barrier: next Phase A writes PQt (last read before bar2); sv next
    // written in Phase B after bar1; Xb is read-only.
  }

  // ========== epilogue: fused (bias+BN) scale/shift + residual + ReLU ==========
  {
    const int trow = wave >> 1;
    const int tcb  = wave & 1;
    float* obase = out + (long)n * 480000 + t0 * 25;
    #pragma unroll
    for (int rg = 0; rg < 4; ++rg) {
      int ob = trow * 32 + rg * 8 + hl * 4;   // 4 contiguous o starting here
      f4 sc = *(const f4*)(sclp + ob);
      f4 sh = *(const f4*)(shf2p + ob);
      #pragma unroll
      for (int tix = 0; tix < 2; ++tix) {
        int col = (tcb + tix * 2) * 32 + l31;
        if (col < COLS) {
          bf4 res = *(const bf4*)&Xb[col * XROW + ob];
          #pragma unroll
          for (int r = 0; r < 4; ++r) {
            float acc = tix ? R1[rg * 4 + r] : R0[rg * 4 + r];
            float h = acc * sc[r] + sh[r] + bf2f(res[r]);
            obase[(long)(ob + r) * 7500 + col] = fmaxf(h, 0.f);
          }
        }
      }
    }
  }
}

extern "C" void kernel_launch(void* const* d_in, const int* in_sizes, int n_in,
                              void* d_out, int out_size, void* d_ws, size_t ws_size,
                              hipStream_t stream) {
  (void)in_sizes; (void)n_in; (void)ws_size; (void)out_size;
  char* ws = (char*)d_ws;
  short* aw_bf = (short*)(ws + WS_AW);
  short* bw_bf = (short*)(ws + WS_BW);
  short* gw_bf = (short*)(ws + WS_GW);
  float* colA3 = (float*)(ws + WS_COLA);
  float* scl   = (float*)(ws + WS_SCL);
  float* shf2  = (float*)(ws + WS_SHF);

  tagc_prep<<<dim3(16), dim3(256), 0, stream>>>(
      (const float*)d_in[1],  (const float*)d_in[2],   // A, graph_attn
      (const float*)d_in[3],  (const float*)d_in[4],   // g_w, g_b
      (const float*)d_in[5],  (const float*)d_in[7],   // a_w, b_w
      (const float*)d_in[9],  (const float*)d_in[10],  // bn_gamma, bn_beta
      (const float*)d_in[11], (const float*)d_in[12],  // bn_mean, bn_var
      aw_bf, bw_bf, gw_bf, colA3, scl, shf2);

  dim3 grid(300 / TT, 64);   // 60 x 64
  tagc_v5_kernel<<<grid, dim3(256), 0, stream>>>(
      (const float*)d_in[0],                           // x
      (const float*)d_in[6],  (const float*)d_in[8],   // a_b, b_b
      aw_bf, bw_bf, gw_bf, colA3, scl, shf2,
      (float*)d_out);
}